// Round 1
// 149.033 us; speedup vs baseline: 1.0739x; 1.0739x over previous
//
#include <hip/hip_runtime.h>
#include <math.h>

// Problem constants
#define BN   4
#define CN   256
#define HN   128
#define WN   128
#define COMP 64
#define KK   25      // K*K taps
#define HO   64
#define WO   64

// ---------------- workspace layout (float offsets) ----------------
// wA : 9*16*64*8 bf16 A-fragments = 36864 float slots
// tb : 225 floats (+pad to 256)
#define TB_OFF    36864
#define WS_NEED   ((size_t)(TB_OFF + 256) * 4)

typedef short v8s  __attribute__((ext_vector_type(8)));
typedef float v16f __attribute__((ext_vector_type(16)));

__device__ inline ushort f2bf(float f) {       // fp32 -> bf16 bits, RNE
  unsigned u = __float_as_uint(f);
  return (ushort)((u + 0x7fffu + ((u >> 16) & 1u)) >> 16);
}

// ---------------------------------------------------------------------------
// Compose kernel (36 blocks x 256 thr): wA MFMA A-fragments (bf16) + tb.
// Same math/layout as the proven prep compose branch.
// ---------------------------------------------------------------------------
__global__ __launch_bounds__(256) void compose_kernel(
    const float* __restrict__ w1, const float* __restrict__ b1,
    const float* __restrict__ w2, float* __restrict__ ws) {
  const int cid = blockIdx.x;                  // 0..35
  const int tid = threadIdx.x;
  const int t = cid >> 2;                      // 0..8
  const int chunk = (cid & 3) * 4 + (tid >> 6);// 0..15 (16-ch group)
  const int lane = tid & 63;
  const int m = lane & 31, half = lane >> 5;
  const int c0 = chunk * 16 + half * 8;
  float acc[8] = {0.f, 0.f, 0.f, 0.f, 0.f, 0.f, 0.f, 0.f};
  if (m < KK) {
    for (int k = 0; k < COMP; ++k) {
      float wv = w2[(size_t)(m * COMP + k) * 9 + t];
      const float* w1r = w1 + (size_t)k * CN + c0;
      float4 a = *(const float4*)w1r;
      float4 bq = *(const float4*)(w1r + 4);
      acc[0] += wv * a.x;  acc[1] += wv * a.y;
      acc[2] += wv * a.z;  acc[3] += wv * a.w;
      acc[4] += wv * bq.x; acc[5] += wv * bq.y;
      acc[6] += wv * bq.z; acc[7] += wv * bq.w;
    }
  }
  ushort* wA = (ushort*)ws;
  ushort pk[8];
#pragma unroll
  for (int j = 0; j < 8; ++j) pk[j] = f2bf(acc[j]);
  *(ushort4*)(wA + ((size_t)(t * 16 + chunk) * 64 + lane) * 8) =
      make_ushort4(pk[0], pk[1], pk[2], pk[3]);
  *(ushort4*)(wA + ((size_t)(t * 16 + chunk) * 64 + lane) * 8 + 4) =
      make_ushort4(pk[4], pk[5], pk[6], pk[7]);
  if (chunk == 0 && lane < KK) {
    float tbv = 0.f;
    for (int k = 0; k < COMP; ++k)
      tbv += w2[(size_t)(lane * COMP + k) * 9 + t] * b1[k];
    ws[TB_OFF + lane * 9 + t] = tbv;
  }
}

// ---------------------------------------------------------------------------
// Fully fused kernel: NCHW->bf16 LDS staging + conv MFMA + softmax + gather.
// grid (HO, BN), 1024 thr = 16 waves.
//
// Conv: 4 chunks of 64 channels. Per chunk: all 1024 threads stage
// x[b][chunk*64..][2ho-1..2ho+1][0..127] -> LDS bf16 [3][128px][64ch],
// XOR-swizzled (slot ^= (px>>1)&7 at 16B granularity) so both the b128
// writes and the stride-2-px b128 B-frag reads stay low-conflict.
// Wave wv: kfrag = wv&3 (16 ch of the chunk), tapgroup = wv>>2
// ({0,1},{2,3},{4,5},{6,7,8}); each wave does both 32-px tiles, so acc
// covers all 64 cols -> reduction tree identical to proven version.
// Next-chunk global loads issue before MFMA (latency hidden under compute).
// LDS reused: stage buf 49152 B, then red 51200 B + sml 6400 B (57600 B).
// C/D layout: col(px)=lane&31, row(m)=(reg&3)+8*(reg>>2)+4*(lane>>5).
// ---------------------------------------------------------------------------
__global__ __launch_bounds__(1024, 4) void fused_main(
    const float* __restrict__ ws, const float* __restrict__ b2,
    const float* __restrict__ x, float* __restrict__ out) {
  const int ho = blockIdx.x, b = blockIdx.y;
  const int tid = threadIdx.x;
  const int lane = tid & 63;
  const int wv = tid >> 6;                     // 0..15
  const int n = lane & 31, half = lane >> 5;

  __shared__ __attribute__((aligned(16))) char smem[57600];
  float* red = (float*)smem;                   // 8*KK*64 floats = 51200 B
  float* sml = (float*)(smem + 51200);         // KK*64 floats   =  6400 B

  const ushort* wA = (const ushort*)ws;
  const float* __restrict__ xb = x + (size_t)(b * CN) * (HN * WN);

  // ---------------- staging (regs) ----------------
  const int px = tid & 127;                    // 0..127
  const int cg = tid >> 7;                     // 0..7 (8-ch subgroup)
  float sreg[3][8];

  auto stage_load = [&](int c) {
#pragma unroll
    for (int dr = 0; dr < 3; ++dr) {
      const int r = 2 * ho + dr - 1;
      if (r >= 0) {                            // block-uniform
        const float* xp = xb + ((size_t)(c * 64 + cg * 8) * HN + r) * WN + px;
#pragma unroll
        for (int i = 0; i < 8; ++i) sreg[dr][i] = xp[(size_t)i * (HN * WN)];
      } else {
#pragma unroll
        for (int i = 0; i < 8; ++i) sreg[dr][i] = 0.f;
      }
    }
  };
  auto stage_write = [&]() {
#pragma unroll
    for (int dr = 0; dr < 3; ++dr) {
      v8s o;
#pragma unroll
      for (int i = 0; i < 8; ++i) o[i] = (short)f2bf(sreg[dr][i]);
      const int boff = (((dr * 128 + px) * 64 + cg * 8) * 2)
                       ^ (((px >> 1) & 7) << 4);
      *(v8s*)(smem + boff) = o;
    }
  };

  // ---------------- Phase 1: conv via MFMA over 4 ch-chunks ----------------
  const int kf = wv & 3;                       // k-frag within chunk
  const int tg = wv >> 2;                      // tap group
  const v8s zero8 = {};
  v16f acc[2] = {{}, {}};

  stage_load(0);
  for (int c = 0; c < 4; ++c) {
    __syncthreads();                           // LDS free (prev chunk read)
    stage_write();
    __syncthreads();                           // LDS ready
    if (c < 3) stage_load(c + 1);              // issue next loads, fly under MFMA
    const int kidx = c * 4 + kf;               // global 16-ch group 0..15
#pragma unroll
    for (int t = 0; t < 9; ++t) {
      const int tgt = (t >= 6) ? 3 : (t >> 1);
      if (tgt != tg) continue;                 // wave-uniform
      const int dr = t / 3, dc = t % 3;
      if (2 * ho + dr - 1 < 0) continue;       // block-uniform (ho==0, dr==0)
      const v8s af = *(const v8s*)(wA + ((size_t)(t * 16 + kidx) * 64 + lane) * 8);
#pragma unroll
      for (int wt = 0; wt < 2; ++wt) {
        const int q = 2 * (wt * 32 + n) + dc - 1;
        const bool bad = q < 0;                // only lane n==0, wt==0, dc==0
        const int qc = bad ? 0 : q;
        const int boff = (((dr * 128 + qc) * 64 + kf * 16 + half * 8) * 2)
                         ^ (((qc >> 1) & 7) << 4);
        v8s bf = *(const v8s*)(smem + boff);
        if (dc == 0 && bad) bf = zero8;
        acc[wt] = __builtin_amdgcn_mfma_f32_32x32x16_bf16(af, bf, acc[wt], 0, 0, 0);
      }
    }
  }

  // ---------------- prefetch gather x loads (fly during tree+softmax) ------
  const int wo = lane;
  const int c_base = __builtin_amdgcn_readfirstlane(wv * 16);
  const int col = 2 * wo;
  float2 g[2][5];
  auto load_g = [&](int ci, float2* dst) {
    const float* xc = xb + (size_t)(c_base + ci) * (HN * WN);
#pragma unroll
    for (int i = 0; i < 5; ++i) {
      int r = 2 * ho - 2 + i;
      dst[i] = (r >= 0 && r < HN) ? *(const float2*)(xc + r * WN + col)
                                  : make_float2(0.f, 0.f);
    }
  };
  load_g(0, g[0]);
  load_g(1, g[1]);

  __syncthreads();                             // stage buf -> red transition

  // ---------------- Reduction 16 -> 8 -> 4 -> 2, then softmax --------------
  if (wv >= 8) {
#pragma unroll
    for (int wt = 0; wt < 2; ++wt)
#pragma unroll
      for (int rg = 0; rg < 16; ++rg) {
        int m = (rg & 3) + 8 * (rg >> 2) + 4 * half;
        if (m < KK) red[((wv - 8) * KK + m) * 64 + wt * 32 + n] = acc[wt][rg];
      }
  }
  __syncthreads();
  if (wv < 8) {
#pragma unroll
    for (int wt = 0; wt < 2; ++wt)
#pragma unroll
      for (int rg = 0; rg < 16; ++rg) {
        int m = (rg & 3) + 8 * (rg >> 2) + 4 * half;
        if (m < KK) red[(wv * KK + m) * 64 + wt * 32 + n] += acc[wt][rg];
      }
  }
  __syncthreads();
  if (wv < 4) {
#pragma unroll
    for (int m = 0; m < KK; ++m)
      red[(wv * KK + m) * 64 + wo] += red[((wv + 4) * KK + m) * 64 + wo];
  }
  __syncthreads();
  if (wv < 2) {
#pragma unroll
    for (int m = 0; m < KK; ++m)
      red[(wv * KK + m) * 64 + wo] += red[((wv + 2) * KK + m) * 64 + wo];
  }
  __syncthreads();
  if (tid < 64) {
    const float* tb = ws + TB_OFF;
    const float vr0 = (ho > 0) ? 1.f : 0.f;
    const float vq0 = (wo > 0) ? 1.f : 0.f;
    float logit[KK];
    float mx = -1e30f;
#pragma unroll
    for (int m = 0; m < KK; ++m) {
      const float* t9 = tb + m * 9;
      float l = b2[m]
              + vr0 * (vq0 * t9[0] + t9[1] + t9[2])
              +       (vq0 * t9[3] + t9[4] + t9[5])
              +       (vq0 * t9[6] + t9[7] + t9[8]);
      l += red[(0 * KK + m) * 64 + wo] + red[(1 * KK + m) * 64 + wo];
      logit[m] = l;
      mx = fmaxf(mx, l);
    }
    float ssum = 0.f;
#pragma unroll
    for (int m = 0; m < KK; ++m) {
      float e = __expf(logit[m] - mx);
      logit[m] = e;
      ssum += e;
    }
    float inv = 1.f / ssum;
#pragma unroll
    for (int m = 0; m < KK; ++m) sml[m * 64 + wo] = logit[m] * inv;
  }
  __syncthreads();

  // ---------------- Phase 2: CARAFE gather ----------------
  float smr[KK];
#pragma unroll
  for (int m = 0; m < KK; ++m) smr[m] = sml[m * 64 + wo];

  const float wok = (wo > 0) ? 1.f : 0.f;
  const float w63 = (wo < 63) ? 1.f : 0.f;
  for (int ci = 0; ci < 16; ++ci) {
    float2 v[5];
#pragma unroll
    for (int i = 0; i < 5; ++i) v[i] = g[ci & 1][i];
    if (ci + 2 < 16) load_g(ci + 2, g[ci & 1]);

    float acc2 = 0.f;
#pragma unroll
    for (int i = 0; i < 5; ++i) {
      float lx = wok * __shfl_up(v[i].x, 1, 64);    // col 2wo-2
      float ly = wok * __shfl_up(v[i].y, 1, 64);    // col 2wo-1
      float rx = w63 * __shfl_down(v[i].x, 1, 64);  // col 2wo+2
      acc2 += lx * smr[i * 5 + 0] + ly * smr[i * 5 + 1]
            + v[i].x * smr[i * 5 + 2] + v[i].y * smr[i * 5 + 3]
            + rx * smr[i * 5 + 4];
    }
    out[(((size_t)(b * CN + c_base + ci)) * HO + ho) * WO + wo] = acc2;
  }
}

// ============================ FALLBACK PATH ================================
// Round-2 proven kernels (used only if ws_size < WS_NEED).
#define FB_WSTRIDE 240
#define FB_TB_OFF  (256 * FB_WSTRIDE)

__global__ __launch_bounds__(256) void compose_w_fb(
    const float* __restrict__ w1, const float* __restrict__ b1,
    const float* __restrict__ w2, float* __restrict__ ws) {
  int mt = blockIdx.x, c = threadIdx.x;
  float acc = 0.f;
#pragma unroll 8
  for (int k = 0; k < COMP; ++k)
    acc += w2[(size_t)(mt / 9 * COMP + k) * 9 + (mt % 9)] * w1[k * CN + c];
  ws[c * FB_WSTRIDE + mt] = acc;
  if (mt < FB_WSTRIDE - 225) ws[c * FB_WSTRIDE + 225 + mt] = 0.f;
  if (c == 0) {
    float tbv = 0.f;
    for (int k = 0; k < COMP; ++k)
      tbv += w2[(size_t)(mt / 9 * COMP + k) * 9 + (mt % 9)] * b1[k];
    ws[FB_TB_OFF + mt] = tbv;
  }
}

__global__ __launch_bounds__(1024, 4) void fused_fb(
    const float* __restrict__ x, const float* __restrict__ b2,
    const float* __restrict__ ws, float* __restrict__ out) {
  const int ho = blockIdx.x, b = blockIdx.y, tid = threadIdx.x;
  const int wo = tid & 63, wv = tid >> 6;
  const int c_base = __builtin_amdgcn_readfirstlane(wv * 16);
  const float* __restrict__ w2c = ws;
  const float* __restrict__ tb  = ws + FB_TB_OFF;
  __shared__ float red[8 * KK * 64];
  __shared__ float sm[KK * 64];
  const float* __restrict__ xb = x + (size_t)(b * CN) * (HN * WN);
  const int col = 2 * wo;
  float acc[KK];
#pragma unroll
  for (int m = 0; m < KK; ++m) acc[m] = 0.f;
  float2 xbuf[2][3];
  auto load_ch = [&](int ci, float2* dst) {
    const float* xc = xb + (size_t)(c_base + ci) * (HN * WN);
    dst[0] = (ho > 0) ? *(const float2*)(xc + (2 * ho - 1) * WN + col)
                      : make_float2(0.f, 0.f);
    dst[1] = *(const float2*)(xc + (2 * ho) * WN + col);
    dst[2] = *(const float2*)(xc + (2 * ho + 1) * WN + col);
  };
  load_ch(0, xbuf[0]);
  load_ch(1, xbuf[1]);
  const float wok = (wo > 0) ? 1.f : 0.f;
  for (int ci = 0; ci < 16; ++ci) {
    float2 r0 = xbuf[ci & 1][0], r1 = xbuf[ci & 1][1], r2 = xbuf[ci & 1][2];
    if (ci + 2 < 16) load_ch(ci + 2, xbuf[ci & 1]);
    float xv[9];
    xv[0] = wok * __shfl_up(r0.y, 1, 64); xv[1] = r0.x; xv[2] = r0.y;
    xv[3] = wok * __shfl_up(r1.y, 1, 64); xv[4] = r1.x; xv[5] = r1.y;
    xv[6] = wok * __shfl_up(r2.y, 1, 64); xv[7] = r2.x; xv[8] = r2.y;
    const float* __restrict__ wrow = w2c + (size_t)(c_base + ci) * FB_WSTRIDE;
#pragma unroll
    for (int m = 0; m < KK; ++m) {
      float a = acc[m];
#pragma unroll
      for (int t = 0; t < 9; ++t) a += wrow[m * 9 + t] * xv[t];
      acc[m] = a;
    }
  }
  float2 g[2][5];
  auto load_g = [&](int ci, float2* dst) {
    const float* xc = xb + (size_t)(c_base + ci) * (HN * WN);
#pragma unroll
    for (int i = 0; i < 5; ++i) {
      int r = 2 * ho - 2 + i;
      dst[i] = (r >= 0 && r < HN) ? *(const float2*)(xc + r * WN + col)
                                  : make_float2(0.f, 0.f);
    }
  };
  load_g(0, g[0]);
  load_g(1, g[1]);
  if (wv >= 8) {
#pragma unroll
    for (int m = 0; m < KK; ++m) red[((wv - 8) * KK + m) * 64 + wo] = acc[m];
  }
  __syncthreads();
  if (wv < 8) {
#pragma unroll
    for (int m = 0; m < KK; ++m) red[(wv * KK + m) * 64 + wo] += acc[m];
  }
  __syncthreads();
  if (wv < 4) {
#pragma unroll
    for (int m = 0; m < KK; ++m)
      red[(wv * KK + m) * 64 + wo] += red[((wv + 4) * KK + m) * 64 + wo];
  }
  __syncthreads();
  if (wv < 2) {
#pragma unroll
    for (int m = 0; m < KK; ++m)
      red[(wv * KK + m) * 64 + wo] += red[((wv + 2) * KK + m) * 64 + wo];
  }
  __syncthreads();
  if (tid < 64) {
    const float vr0 = (ho > 0) ? 1.f : 0.f;
    const float vq0 = (wo > 0) ? 1.f : 0.f;
    float logit[KK];
    float mx = -1e30f;
#pragma unroll
    for (int m = 0; m < KK; ++m) {
      const float* t9 = tb + m * 9;
      float l = b2[m]
              + vr0 * (vq0 * t9[0] + t9[1] + t9[2])
              +       (vq0 * t9[3] + t9[4] + t9[5])
              +       (vq0 * t9[6] + t9[7] + t9[8]);
      l += red[(0 * KK + m) * 64 + wo] + red[(1 * KK + m) * 64 + wo];
      logit[m] = l;
      mx = fmaxf(mx, l);
    }
    float s = 0.f;
#pragma unroll
    for (int m = 0; m < KK; ++m) {
      float e = __expf(logit[m] - mx);
      logit[m] = e;
      s += e;
    }
    float inv = 1.f / s;
#pragma unroll
    for (int m = 0; m < KK; ++m) sm[m * 64 + wo] = logit[m] * inv;
  }
  __syncthreads();
  float smr[KK];
#pragma unroll
  for (int m = 0; m < KK; ++m) smr[m] = sm[m * 64 + wo];
  const float w63 = (wo < 63) ? 1.f : 0.f;
  for (int ci = 0; ci < 16; ++ci) {
    float2 v[5];
#pragma unroll
    for (int i = 0; i < 5; ++i) v[i] = g[ci & 1][i];
    if (ci + 2 < 16) load_g(ci + 2, g[ci & 1]);
    float acc2 = 0.f;
#pragma unroll
    for (int i = 0; i < 5; ++i) {
      float lx = wok * __shfl_up(v[i].x, 1, 64);
      float ly = wok * __shfl_up(v[i].y, 1, 64);
      float rx = w63 * __shfl_down(v[i].x, 1, 64);
      acc2 += lx * smr[i * 5 + 0] + ly * smr[i * 5 + 1]
            + v[i].x * smr[i * 5 + 2] + v[i].y * smr[i * 5 + 3]
            + rx * smr[i * 5 + 4];
    }
    out[(((size_t)(b * CN + c_base + ci)) * HO + ho) * WO + wo] = acc2;
  }
}

// ---------------------------------------------------------------------------
extern "C" void kernel_launch(void* const* d_in, const int* in_sizes, int n_in,
                              void* d_out, int out_size, void* d_ws, size_t ws_size,
                              hipStream_t stream) {
  const float* x  = (const float*)d_in[0];
  const float* w1 = (const float*)d_in[1];
  const float* b1 = (const float*)d_in[2];
  const float* w2 = (const float*)d_in[3];
  const float* b2 = (const float*)d_in[4];
  float* out = (float*)d_out;
  float* ws  = (float*)d_ws;

  if (ws_size >= WS_NEED) {
    hipLaunchKernelGGL(compose_kernel, dim3(36), dim3(256), 0, stream,
                       w1, b1, w2, ws);
    hipLaunchKernelGGL(fused_main, dim3(HO, BN), dim3(1024), 0, stream,
                       ws, b2, x, out);
  } else {
    hipLaunchKernelGGL(compose_w_fb, dim3(225), dim3(256), 0, stream,
                       w1, b1, w2, ws);
    hipLaunchKernelGGL(fused_fb, dim3(HO, BN), dim3(1024), 0, stream,
                       x, b2, ws, out);
  }
}